// Round 11
// baseline (560.195 us; speedup 1.0000x reference)
//
#include <hip/hip_runtime.h>
#include <hip/hip_bf16.h>
#include <stdint.h>

typedef unsigned short u16;
typedef __attribute__((ext_vector_type(8))) short short8;
typedef __attribute__((ext_vector_type(4))) float f32x4;

#define DIM 128
#define CAP 64   // per-node bucket capacity; deg ~ Poisson(16), P(deg>=64) ~ 2e-18/node

__device__ __forceinline__ float bflo(uint32_t v) {
    uint32_t b = v << 16;
    float f; __builtin_memcpy(&f, &b, 4); return f;
}
__device__ __forceinline__ float bfhi(uint32_t v) {
    uint32_t b = v & 0xffff0000u;
    float f; __builtin_memcpy(&f, &b, 4); return f;
}
__device__ __forceinline__ u16 f2bf(float f) {
    uint32_t x; __builtin_memcpy(&x, &f, 4);
    uint32_t r = (x + 0x7fffu + ((x >> 16) & 1u)) >> 16;
    return (u16)r;
}
__device__ __forceinline__ uint32_t pack2bf(float a, float b) {
    return (uint32_t)f2bf(a) | ((uint32_t)f2bf(b) << 16);
}

// ---------------- sort-based CSR build (no per-edge global atomics) ----------------

__global__ __launch_bounds__(256) void k_bin1(
    const int* __restrict__ src, const int* __restrict__ dst,
    uint32_t* __restrict__ gCur, uint32_t* __restrict__ groupBuf,
    int E, int ngrp, int gcap)
{
    __shared__ uint32_t hcnt[512];
    __shared__ uint32_t hbase[512];
    __shared__ uint32_t hcur[512];
    int nb = gridDim.x;
    int per = (E + nb - 1) / nb;
    int lo = blockIdx.x * per;
    int hi = lo + per; if (hi > E) hi = E;

    for (int t = threadIdx.x; t < ngrp; t += 256) { hcnt[t] = 0; hcur[t] = 0; }
    __syncthreads();

    for (int i = lo + threadIdx.x; i < hi; i += 256)
        atomicAdd(&hcnt[((uint32_t)dst[i]) >> 8], 1u);
    __syncthreads();

    int rot = (blockIdx.x * 37) % (ngrp > 0 ? ngrp : 1);
    for (int k = threadIdx.x; k < ngrp; k += 256) {
        int t = k + rot; if (t >= ngrp) t -= ngrp;
        uint32_t c = hcnt[t];
        hbase[t] = c ? atomicAdd(&gCur[t], c) : 0u;
    }
    __syncthreads();

    for (int i = lo + threadIdx.x; i < hi; i += 256) {
        uint32_t d = (uint32_t)dst[i];
        uint32_t g = d >> 8;
        uint32_t off = hbase[g] + atomicAdd(&hcur[g], 1u);
        if (off < (uint32_t)gcap)
            groupBuf[(size_t)g * gcap + off] = (uint32_t)src[i] | ((d & 255u) << 20);
    }
}

__global__ __launch_bounds__(256) void k_bin2(
    const uint32_t* __restrict__ groupBuf, const uint32_t* __restrict__ gCur,
    uint32_t* __restrict__ bucket, uint32_t* __restrict__ cnt,
    int N, int gcap)
{
    __shared__ uint32_t ncur[256];
    int g = blockIdx.x;
    ncur[threadIdx.x] = 0;
    __syncthreads();
    uint32_t m = gCur[g]; if (m > (uint32_t)gcap) m = gcap;
    int nodebase = g << 8;
    const uint32_t* buf = groupBuf + (size_t)g * gcap;
    for (uint32_t i = threadIdx.x; i < m; i += 256) {
        uint32_t v = buf[i];
        uint32_t nl = v >> 20;
        uint32_t s = v & 0xFFFFFu;
        uint32_t pos = atomicAdd(&ncur[nl], 1u);   // LDS atomic
        if (pos < CAP) bucket[(size_t)(nodebase + (int)nl) * CAP + pos] = s;
    }
    __syncthreads();
    int node = nodebase + threadIdx.x;
    if (node < N) cnt[node] = ncur[threadIdx.x];
}

// ---------------- feature cast f32 -> bf16 (once per call) ----------------

__global__ void k_cast(const float* __restrict__ in, uint32_t* __restrict__ out, int n4) {
    int i = blockIdx.x * blockDim.x + threadIdx.x;
    int stride = gridDim.x * blockDim.x;
    const float4* in4 = (const float4*)in;
    uint2* out2 = (uint2*)out;
    for (; i < n4; i += stride) {
        float4 v = in4[i];
        uint2 r;
        r.x = pack2bf(v.x, v.y);
        r.y = pack2bf(v.z, v.w);
        out2[i] = r;
    }
}

// ---------------- weight transpose f32 -> bf16 (once per call) ----------------

__global__ void k_transpose3(const float* __restrict__ w0, const float* __restrict__ w1,
                             const float* __restrict__ w2, u16* __restrict__ t0,
                             u16* __restrict__ t1, u16* __restrict__ t2) {
    const float* w = blockIdx.x == 0 ? w0 : (blockIdx.x == 1 ? w1 : w2);
    u16* o = blockIdx.x == 0 ? t0 : (blockIdx.x == 1 ? t1 : t2);
    for (int idx = threadIdx.x; idx < DIM * DIM; idx += blockDim.x) {
        int r = idx >> 7, c = idx & 127;
        o[c * DIM + r] = f2bf(w[idx]);
    }
}

// ---------------- gather (segment_sum pull) + LayerNorm fused ----------------
// One wave per NODE PAIR (adjacent nodes, plain bucket layout); lane = dims {2l,2l+1}.
// Per iteration: 16+16 UNCONDITIONAL loads (idx clamped to 0; value zeroed by AND
// mask) -> 32 independent loads in flight, no branches inside the batch.
// Requires bucket zero-initialized (clamped reads of empty nodes hit slot 0 = 0).

__global__ __launch_bounds__(256) void k_gather_ln(
    const uint32_t* __restrict__ xin, const uint32_t* __restrict__ cnt,
    const uint32_t* __restrict__ bucket,
    const int* __restrict__ src, const int* __restrict__ dst,
    const float* __restrict__ gamma, const float* __restrict__ beta,
    uint32_t* __restrict__ h, int N, int E)
{
    int w = threadIdx.x >> 6, l = threadIdx.x & 63;
    int p = blockIdx.x * 4 + w;
    int node0 = 2 * p, node1 = node0 + 1;
    if (node0 >= N) return;
    bool has1 = node1 < N;
    uint32_t c0 = cnt[node0];
    uint32_t c1 = has1 ? cnt[node1] : 0u;
    float a0 = 0.f, a1 = 0.f, b0 = 0.f, b1 = 0.f;

    if (__builtin_expect(c0 > CAP || c1 > CAP, 0)) {
        // overflow fallback: raw edge scan (never in practice)
        for (int e = 0; e < E; ++e) {
            int d = dst[e];
            if (d == node0) { uint32_t v = xin[(size_t)src[e] * 64 + l]; a0 += bflo(v); a1 += bfhi(v); }
            else if (d == node1) { uint32_t v = xin[(size_t)src[e] * 64 + l]; b0 += bflo(v); b1 += bfhi(v); }
        }
    } else {
        const uint32_t* bkt0 = bucket + (size_t)node0 * CAP;
        const uint32_t* bkt1 = has1 ? bucket + (size_t)node1 * CAP : bkt0;
        uint32_t e = 0;
        while (e < c0 || e < c1) {
            uint32_t v0[16], v1[16];
#pragma unroll
            for (int i = 0; i < 16; ++i) {
                uint32_t idx = e + (uint32_t)i;
                uint32_t i0 = idx < c0 ? idx : 0u;
                v0[i] = xin[(size_t)bkt0[i0] * 64 + l];
            }
#pragma unroll
            for (int i = 0; i < 16; ++i) {
                uint32_t idx = e + (uint32_t)i;
                uint32_t i1 = idx < c1 ? idx : 0u;
                v1[i] = xin[(size_t)bkt1[i1] * 64 + l];
            }
#pragma unroll
            for (int i = 0; i < 16; ++i) {
                uint32_t m0 = (e + (uint32_t)i < c0) ? 0xffffffffu : 0u;
                uint32_t m1 = (e + (uint32_t)i < c1) ? 0xffffffffu : 0u;
                uint32_t x0 = v0[i] & m0;
                uint32_t x1 = v1[i] & m1;
                a0 += bflo(x0); a1 += bfhi(x0);
                b0 += bflo(x1); b1 += bfhi(x1);
            }
            e += 16;
        }
    }

    float gg0 = gamma[2 * l], gg1 = gamma[2 * l + 1];
    float bb0 = beta[2 * l],  bb1 = beta[2 * l + 1];

    // LN node0
    {
        float sum = a0 + a1, sq = a0 * a0 + a1 * a1;
        for (int off = 32; off; off >>= 1) {
            sum += __shfl_xor(sum, off, 64);
            sq  += __shfl_xor(sq,  off, 64);
        }
        float mean = sum * (1.f / 128.f);
        float var  = sq * (1.f / 128.f) - mean * mean;
        float rs   = rsqrtf(var + 1e-5f);
        float h0 = (a0 - mean) * rs * gg0 + bb0;
        float h1 = (a1 - mean) * rs * gg1 + bb1;
        h[(size_t)node0 * 64 + l] = pack2bf(h0, h1);
    }
    // LN node1
    if (has1) {
        float sum = b0 + b1, sq = b0 * b0 + b1 * b1;
        for (int off = 32; off; off >>= 1) {
            sum += __shfl_xor(sum, off, 64);
            sq  += __shfl_xor(sq,  off, 64);
        }
        float mean = sum * (1.f / 128.f);
        float var  = sq * (1.f / 128.f) - mean * mean;
        float rs   = rsqrtf(var + 1e-5f);
        float h0 = (b0 - mean) * rs * gg0 + bb0;
        float h1 = (b1 - mean) * rs * gg1 + bb1;
        h[(size_t)node1 * 64 + l] = pack2bf(h0, h1);
    }
}

// ---------------- persistent GEMM: out = relu?(h @ W + b) via MFMA ----------------
// Grid-stride over 32-row tiles; B-fragments + bias hoisted (loaded once per block).

template <int RELU, int OUTF32>
__global__ __launch_bounds__(256) void k_gemm(
    const u16* __restrict__ h, const u16* __restrict__ wt,
    const float* __restrict__ bias, void* __restrict__ outp, int N)
{
    int w = threadIdx.x >> 6, l = threadIdx.x & 63;
    int colbase = (w >> 1) * 64;
    int lr = l & 15, lg = l >> 4;

    short8 bfrag[4][4];
    float bv[4];
#pragma unroll
    for (int ct = 0; ct < 4; ++ct) {
        bv[ct] = bias[colbase + ct * 16 + lr];
#pragma unroll
        for (int kc = 0; kc < 4; ++kc)
            bfrag[ct][kc] = *(const short8*)(wt + (size_t)(colbase + ct * 16 + lr) * DIM + kc * 32 + lg * 8);
    }

    int ntiles = (N + 31) / 32;
    for (int t = blockIdx.x; t < ntiles; t += gridDim.x) {
        int row0 = t * 32 + 16 * (w & 1);
        int ar = row0 + lr;
        if (ar > N - 1) ar = N - 1;

        short8 afrag[4];
#pragma unroll
        for (int kc = 0; kc < 4; ++kc)
            afrag[kc] = *(const short8*)(h + (size_t)ar * DIM + kc * 32 + lg * 8);

#pragma unroll
        for (int ct = 0; ct < 4; ++ct) {
            f32x4 a = {0.f, 0.f, 0.f, 0.f};
#pragma unroll
            for (int kc = 0; kc < 4; ++kc)
                a = __builtin_amdgcn_mfma_f32_16x16x32_bf16(afrag[kc], bfrag[ct][kc], a, 0, 0, 0);
            int col = colbase + ct * 16 + lr;
#pragma unroll
            for (int j = 0; j < 4; ++j) {
                int row = row0 + lg * 4 + j;
                float v = a[j] + bv[ct];
                if (RELU) v = fmaxf(v, 0.f);
                if (row < N) {
                    if (OUTF32) ((float*)outp)[(size_t)row * DIM + col] = v;
                    else        ((u16*)outp)[(size_t)row * DIM + col] = f2bf(v);
                }
            }
        }
    }
}

// ---------------- launch ----------------

extern "C" void kernel_launch(void* const* d_in, const int* in_sizes, int n_in,
                              void* d_out, int out_size, void* d_ws, size_t ws_size,
                              hipStream_t stream) {
    const float* feat = (const float*)d_in[0];
    const int* src  = (const int*)d_in[1];
    const int* dst  = (const int*)d_in[2];
    const float* g1 = (const float*)d_in[3],  *be1 = (const float*)d_in[4];
    const float* W1 = (const float*)d_in[5],  *b1  = (const float*)d_in[6];
    const float* g2 = (const float*)d_in[7],  *be2 = (const float*)d_in[8];
    const float* W2 = (const float*)d_in[9],  *b2  = (const float*)d_in[10];
    const float* g3 = (const float*)d_in[11], *be3 = (const float*)d_in[12];
    const float* W3 = (const float*)d_in[13], *b3  = (const float*)d_in[14];

    int N = in_sizes[0] / DIM;
    int E = in_sizes[1];
    float* out = (float*)d_out;

    int ngrp = (N + 255) >> 8;                 // 391 for N=100000 (max 512)
    int gcap = (E / (ngrp > 0 ? ngrp : 1)) * 3 / 2 + 1024;
    int npair = (N + 1) / 2;

    char* ws = (char*)d_ws;
    auto alloc = [&](size_t bytes) {
        char* p = ws;
        ws += (bytes + 255) & ~(size_t)255;
        return p;
    };
    uint32_t* gCur     = (uint32_t*)alloc((size_t)ngrp * 4);
    uint32_t* groupBuf = (uint32_t*)alloc((size_t)ngrp * gcap * 4);
    uint32_t* cnt      = (uint32_t*)alloc((size_t)N * 4);
    uint32_t* bucket   = (uint32_t*)alloc((size_t)N * CAP * 4);
    u16* wt1 = (u16*)alloc(DIM * DIM * 2);
    u16* wt2 = (u16*)alloc(DIM * DIM * 2);
    u16* wt3 = (u16*)alloc(DIM * DIM * 2);
    uint32_t* X0 = (uint32_t*)alloc((size_t)N * 64 * 4);  // bf16-packed features
    uint32_t* H  = (uint32_t*)alloc((size_t)N * 64 * 4);  // bf16-packed LN out
    uint32_t* X  = (uint32_t*)alloc((size_t)N * 64 * 4);  // bf16-packed layer out

    hipMemsetAsync(gCur, 0, (size_t)ngrp * 4, stream);
    hipMemsetAsync(bucket, 0, (size_t)N * CAP * 4, stream);  // clamped reads need valid slot 0
    k_bin1<<<256, 256, 0, stream>>>(src, dst, gCur, groupBuf, E, ngrp, gcap);
    k_bin2<<<ngrp, 256, 0, stream>>>(groupBuf, gCur, bucket, cnt, N, gcap);
    k_transpose3<<<3, 256, 0, stream>>>(W1, W2, W3, wt1, wt2, wt3);
    k_cast<<<1024, 256, 0, stream>>>(feat, X0, N * 32);

    int gblocks = (npair + 3) / 4;

    // gather reads X (or X0) and writes H; gemm reads H and writes X — never aliased
    k_gather_ln<<<gblocks, 256, 0, stream>>>(X0, cnt, bucket, src, dst, g1, be1, H, N, E);
    k_gemm<1, 0><<<512, 256, 0, stream>>>((const u16*)H, wt1, b1, X, N);
    k_gather_ln<<<gblocks, 256, 0, stream>>>(X, cnt, bucket, src, dst, g2, be2, H, N, E);
    k_gemm<1, 0><<<512, 256, 0, stream>>>((const u16*)H, wt2, b2, X, N);
    k_gather_ln<<<gblocks, 256, 0, stream>>>(X, cnt, bucket, src, dst, g3, be3, H, N, E);
    k_gemm<0, 1><<<512, 256, 0, stream>>>((const u16*)H, wt3, b3, out, N);
}

// Round 12
// 315.429 us; speedup vs baseline: 1.7760x; 1.7760x over previous
//
#include <hip/hip_runtime.h>
#include <hip/hip_bf16.h>
#include <stdint.h>

typedef unsigned short u16;
typedef __attribute__((ext_vector_type(8))) short short8;
typedef __attribute__((ext_vector_type(4))) float f32x4;

#define DIM 128
#define CAP 64   // per-node bucket capacity; deg ~ Poisson(16), P(deg>=64) ~ 2e-18/node

__device__ __forceinline__ float bflo(uint32_t v) {
    uint32_t b = v << 16;
    float f; __builtin_memcpy(&f, &b, 4); return f;
}
__device__ __forceinline__ float bfhi(uint32_t v) {
    uint32_t b = v & 0xffff0000u;
    float f; __builtin_memcpy(&f, &b, 4); return f;
}
__device__ __forceinline__ u16 f2bf(float f) {
    uint32_t x; __builtin_memcpy(&x, &f, 4);
    uint32_t r = (x + 0x7fffu + ((x >> 16) & 1u)) >> 16;
    return (u16)r;
}
__device__ __forceinline__ uint32_t pack2bf(float a, float b) {
    return (uint32_t)f2bf(a) | ((uint32_t)f2bf(b) << 16);
}

// ---------------- sort-based CSR build (no per-edge global atomics) ----------------

__global__ __launch_bounds__(256) void k_bin1(
    const int* __restrict__ src, const int* __restrict__ dst,
    uint32_t* __restrict__ gCur, uint32_t* __restrict__ groupBuf,
    int E, int ngrp, int gcap)
{
    __shared__ uint32_t hcnt[512];
    __shared__ uint32_t hbase[512];
    __shared__ uint32_t hcur[512];
    int nb = gridDim.x;
    int per = (E + nb - 1) / nb;
    int lo = blockIdx.x * per;
    int hi = lo + per; if (hi > E) hi = E;

    for (int t = threadIdx.x; t < ngrp; t += 256) { hcnt[t] = 0; hcur[t] = 0; }
    __syncthreads();

    for (int i = lo + threadIdx.x; i < hi; i += 256)
        atomicAdd(&hcnt[((uint32_t)dst[i]) >> 8], 1u);
    __syncthreads();

    int rot = (blockIdx.x * 37) % (ngrp > 0 ? ngrp : 1);
    for (int k = threadIdx.x; k < ngrp; k += 256) {
        int t = k + rot; if (t >= ngrp) t -= ngrp;
        uint32_t c = hcnt[t];
        hbase[t] = c ? atomicAdd(&gCur[t], c) : 0u;
    }
    __syncthreads();

    for (int i = lo + threadIdx.x; i < hi; i += 256) {
        uint32_t d = (uint32_t)dst[i];
        uint32_t g = d >> 8;
        uint32_t off = hbase[g] + atomicAdd(&hcur[g], 1u);
        if (off < (uint32_t)gcap)
            groupBuf[(size_t)g * gcap + off] = (uint32_t)src[i] | ((d & 255u) << 20);
    }
}

__global__ __launch_bounds__(256) void k_bin2(
    const uint32_t* __restrict__ groupBuf, const uint32_t* __restrict__ gCur,
    uint32_t* __restrict__ bucket, uint32_t* __restrict__ cnt,
    int N, int gcap)
{
    __shared__ uint32_t ncur[256];
    int g = blockIdx.x;
    ncur[threadIdx.x] = 0;
    __syncthreads();
    uint32_t m = gCur[g]; if (m > (uint32_t)gcap) m = gcap;
    int nodebase = g << 8;
    const uint32_t* buf = groupBuf + (size_t)g * gcap;
    for (uint32_t i = threadIdx.x; i < m; i += 256) {
        uint32_t v = buf[i];
        uint32_t nl = v >> 20;
        uint32_t s = v & 0xFFFFFu;
        uint32_t pos = atomicAdd(&ncur[nl], 1u);   // LDS atomic
        if (pos < CAP) bucket[(size_t)(nodebase + (int)nl) * CAP + pos] = s;
    }
    __syncthreads();
    int node = nodebase + threadIdx.x;
    if (node < N) cnt[node] = ncur[threadIdx.x];
}

// ---------------- feature cast f32 -> bf16 (once per call) ----------------

__global__ void k_cast(const float* __restrict__ in, uint32_t* __restrict__ out, int n4) {
    int i = blockIdx.x * blockDim.x + threadIdx.x;
    int stride = gridDim.x * blockDim.x;
    const float4* in4 = (const float4*)in;
    uint2* out2 = (uint2*)out;
    for (; i < n4; i += stride) {
        float4 v = in4[i];
        uint2 r;
        r.x = pack2bf(v.x, v.y);
        r.y = pack2bf(v.z, v.w);
        out2[i] = r;
    }
}

// ---------------- zero row N of X0 and X (invalid-slot target row) ----------------

__global__ void k_zero_row(uint32_t* __restrict__ a, uint32_t* __restrict__ b, int N) {
    int t = threadIdx.x;
    if (t < 64) a[(size_t)N * 64 + t] = 0u;
    else        b[(size_t)N * 64 + (t - 64)] = 0u;
}

// ---------------- weight transpose f32 -> bf16 (once per call) ----------------

__global__ void k_transpose3(const float* __restrict__ w0, const float* __restrict__ w1,
                             const float* __restrict__ w2, u16* __restrict__ t0,
                             u16* __restrict__ t1, u16* __restrict__ t2) {
    const float* w = blockIdx.x == 0 ? w0 : (blockIdx.x == 1 ? w1 : w2);
    u16* o = blockIdx.x == 0 ? t0 : (blockIdx.x == 1 ? t1 : t2);
    for (int idx = threadIdx.x; idx < DIM * DIM; idx += blockDim.x) {
        int r = idx >> 7, c = idx & 127;
        o[c * DIM + r] = f2bf(w[idx]);
    }
}

// ---------------- gather (segment_sum pull) + LayerNorm fused ----------------
// One wave per node; lane handles dims {2l, 2l+1}; f32 accumulation.
// Scalar-engine addressing: wave preloads its 64 bucket slots into lanes (bktv);
// per slot, src index via v_readlane (imm) -> SGPR, validity via scalar cselect
// to the ZERO ROW (index N), row base = scalar, per-lane offset = l*4 fixed.
// 16 loads per group, up to 4 groups (uniform-branch gated).

__global__ __launch_bounds__(256) void k_gather_ln(
    const uint32_t* __restrict__ xin, const uint32_t* __restrict__ cnt,
    const uint32_t* __restrict__ bucket,
    const int* __restrict__ src, const int* __restrict__ dst,
    const float* __restrict__ gamma, const float* __restrict__ beta,
    uint32_t* __restrict__ h, int N, int E)
{
    int w = threadIdx.x >> 6, l = threadIdx.x & 63;
    int node = blockIdx.x * 4 + w;
    if (node >= N) return;
    uint32_t c = cnt[node];
    float a0 = 0.f, a1 = 0.f;

    if (__builtin_expect(c > CAP, 0)) {
        // overflow fallback: raw edge scan (never in practice)
        for (int e = 0; e < E; ++e) {
            if (dst[e] == node) {
                uint32_t v = xin[(size_t)src[e] * 64 + l];
                a0 += bflo(v); a1 += bfhi(v);
            }
        }
    } else {
        // lane l holds bucket slot l (slots >= c are garbage, never dereferenced)
        uint32_t bktv = bucket[(size_t)node * CAP + l];
#pragma unroll
        for (int g = 0; g < 4; ++g) {
            if ((uint32_t)(g * 16) < c) {
                uint32_t v[16];
#pragma unroll
                for (int i = 0; i < 16; ++i) {
                    const int SLOT = g * 16 + i;
                    uint32_t su = (uint32_t)__builtin_amdgcn_readlane(bktv, SLOT); // SGPR
                    su = ((uint32_t)SLOT < c) ? su : (uint32_t)N;  // scalar cselect -> zero row
                    const uint32_t* rowp = xin + (size_t)su * 64;  // scalar base
                    v[i] = rowp[l];                                 // sbase + l*4
                }
#pragma unroll
                for (int i = 0; i < 16; ++i) { a0 += bflo(v[i]); a1 += bfhi(v[i]); }
            }
        }
    }

    float sum = a0 + a1;
    float sq  = a0 * a0 + a1 * a1;
    for (int off = 32; off; off >>= 1) {
        sum += __shfl_xor(sum, off, 64);
        sq  += __shfl_xor(sq,  off, 64);
    }
    float mean = sum * (1.f / 128.f);
    float var  = sq * (1.f / 128.f) - mean * mean;
    float rs   = rsqrtf(var + 1e-5f);
    float g0 = gamma[2 * l], g1 = gamma[2 * l + 1];
    float b0 = beta[2 * l],  b1 = beta[2 * l + 1];
    float h0 = (a0 - mean) * rs * g0 + b0;
    float h1 = (a1 - mean) * rs * g1 + b1;
    h[(size_t)node * 64 + l] = pack2bf(h0, h1);
}

// ---------------- persistent GEMM: out = relu?(h @ W + b) via MFMA ----------------
// Grid-stride over 32-row tiles; B-fragments + bias hoisted (loaded once per block).

template <int RELU, int OUTF32>
__global__ __launch_bounds__(256) void k_gemm(
    const u16* __restrict__ h, const u16* __restrict__ wt,
    const float* __restrict__ bias, void* __restrict__ outp, int N)
{
    int w = threadIdx.x >> 6, l = threadIdx.x & 63;
    int colbase = (w >> 1) * 64;
    int lr = l & 15, lg = l >> 4;

    short8 bfrag[4][4];
    float bv[4];
#pragma unroll
    for (int ct = 0; ct < 4; ++ct) {
        bv[ct] = bias[colbase + ct * 16 + lr];
#pragma unroll
        for (int kc = 0; kc < 4; ++kc)
            bfrag[ct][kc] = *(const short8*)(wt + (size_t)(colbase + ct * 16 + lr) * DIM + kc * 32 + lg * 8);
    }

    int ntiles = (N + 31) / 32;
    for (int t = blockIdx.x; t < ntiles; t += gridDim.x) {
        int row0 = t * 32 + 16 * (w & 1);
        int ar = row0 + lr;
        if (ar > N - 1) ar = N - 1;

        short8 afrag[4];
#pragma unroll
        for (int kc = 0; kc < 4; ++kc)
            afrag[kc] = *(const short8*)(h + (size_t)ar * DIM + kc * 32 + lg * 8);

#pragma unroll
        for (int ct = 0; ct < 4; ++ct) {
            f32x4 a = {0.f, 0.f, 0.f, 0.f};
#pragma unroll
            for (int kc = 0; kc < 4; ++kc)
                a = __builtin_amdgcn_mfma_f32_16x16x32_bf16(afrag[kc], bfrag[ct][kc], a, 0, 0, 0);
            int col = colbase + ct * 16 + lr;
#pragma unroll
            for (int j = 0; j < 4; ++j) {
                int row = row0 + lg * 4 + j;
                float v = a[j] + bv[ct];
                if (RELU) v = fmaxf(v, 0.f);
                if (row < N) {
                    if (OUTF32) ((float*)outp)[(size_t)row * DIM + col] = v;
                    else        ((u16*)outp)[(size_t)row * DIM + col] = f2bf(v);
                }
            }
        }
    }
}

// ---------------- launch ----------------

extern "C" void kernel_launch(void* const* d_in, const int* in_sizes, int n_in,
                              void* d_out, int out_size, void* d_ws, size_t ws_size,
                              hipStream_t stream) {
    const float* feat = (const float*)d_in[0];
    const int* src  = (const int*)d_in[1];
    const int* dst  = (const int*)d_in[2];
    const float* g1 = (const float*)d_in[3],  *be1 = (const float*)d_in[4];
    const float* W1 = (const float*)d_in[5],  *b1  = (const float*)d_in[6];
    const float* g2 = (const float*)d_in[7],  *be2 = (const float*)d_in[8];
    const float* W2 = (const float*)d_in[9],  *b2  = (const float*)d_in[10];
    const float* g3 = (const float*)d_in[11], *be3 = (const float*)d_in[12];
    const float* W3 = (const float*)d_in[13], *b3  = (const float*)d_in[14];

    int N = in_sizes[0] / DIM;
    int E = in_sizes[1];
    float* out = (float*)d_out;

    int ngrp = (N + 255) >> 8;                 // 391 for N=100000 (max 512)
    int gcap = (E / (ngrp > 0 ? ngrp : 1)) * 3 / 2 + 1024;

    char* ws = (char*)d_ws;
    auto alloc = [&](size_t bytes) {
        char* p = ws;
        ws += (bytes + 255) & ~(size_t)255;
        return p;
    };
    uint32_t* gCur     = (uint32_t*)alloc((size_t)ngrp * 4);
    uint32_t* groupBuf = (uint32_t*)alloc((size_t)ngrp * gcap * 4);
    uint32_t* cnt      = (uint32_t*)alloc((size_t)N * 4);
    uint32_t* bucket   = (uint32_t*)alloc((size_t)N * CAP * 4);
    u16* wt1 = (u16*)alloc(DIM * DIM * 2);
    u16* wt2 = (u16*)alloc(DIM * DIM * 2);
    u16* wt3 = (u16*)alloc(DIM * DIM * 2);
    // N+1 rows: row N is the zero row targeted by invalid slots
    uint32_t* X0 = (uint32_t*)alloc((size_t)(N + 1) * 64 * 4);
    uint32_t* H  = (uint32_t*)alloc((size_t)(N + 1) * 64 * 4);
    uint32_t* X  = (uint32_t*)alloc((size_t)(N + 1) * 64 * 4);

    hipMemsetAsync(gCur, 0, (size_t)ngrp * 4, stream);
    k_bin1<<<256, 256, 0, stream>>>(src, dst, gCur, groupBuf, E, ngrp, gcap);
    k_bin2<<<ngrp, 256, 0, stream>>>(groupBuf, gCur, bucket, cnt, N, gcap);
    k_transpose3<<<3, 256, 0, stream>>>(W1, W2, W3, wt1, wt2, wt3);
    k_cast<<<1024, 256, 0, stream>>>(feat, X0, N * 32);
    k_zero_row<<<1, 128, 0, stream>>>(X0, X, N);

    int gblocks = (N + 3) / 4;

    // gather reads X0/X (+ zero row N), writes H; gemm reads H, writes X — never aliased
    k_gather_ln<<<gblocks, 256, 0, stream>>>(X0, cnt, bucket, src, dst, g1, be1, H, N, E);
    k_gemm<1, 0><<<512, 256, 0, stream>>>((const u16*)H, wt1, b1, X, N);
    k_gather_ln<<<gblocks, 256, 0, stream>>>(X, cnt, bucket, src, dst, g2, be2, H, N, E);
    k_gemm<1, 0><<<512, 256, 0, stream>>>((const u16*)H, wt2, b2, X, N);
    k_gather_ln<<<gblocks, 256, 0, stream>>>(X, cnt, bucket, src, dst, g3, be3, H, N, E);
    k_gemm<0, 1><<<512, 256, 0, stream>>>((const u16*)H, wt3, b3, out, N);
}

// Round 13
// 306.148 us; speedup vs baseline: 1.8298x; 1.0303x over previous
//
#include <hip/hip_runtime.h>
#include <hip/hip_bf16.h>
#include <stdint.h>

typedef unsigned short u16;
typedef __attribute__((ext_vector_type(8))) short short8;
typedef __attribute__((ext_vector_type(4))) float f32x4;

#define DIM 128
#define CAP 64   // per-node bucket capacity; deg ~ Poisson(16), P(deg>=64) ~ 2e-18/node

__device__ __forceinline__ float bflo(uint32_t v) {
    uint32_t b = v << 16;
    float f; __builtin_memcpy(&f, &b, 4); return f;
}
__device__ __forceinline__ float bfhi(uint32_t v) {
    uint32_t b = v & 0xffff0000u;
    float f; __builtin_memcpy(&f, &b, 4); return f;
}
__device__ __forceinline__ u16 f2bf(float f) {
    uint32_t x; __builtin_memcpy(&x, &f, 4);
    uint32_t r = (x + 0x7fffu + ((x >> 16) & 1u)) >> 16;
    return (u16)r;
}
__device__ __forceinline__ uint32_t pack2bf(float a, float b) {
    return (uint32_t)f2bf(a) | ((uint32_t)f2bf(b) << 16);
}

// ---------------- sort-based CSR build (no per-edge global atomics) ----------------

__global__ __launch_bounds__(256) void k_bin1(
    const int* __restrict__ src, const int* __restrict__ dst,
    uint32_t* __restrict__ gCur, uint32_t* __restrict__ groupBuf,
    int E, int ngrp, int gcap)
{
    __shared__ uint32_t hcnt[512];
    __shared__ uint32_t hbase[512];
    __shared__ uint32_t hcur[512];
    int nb = gridDim.x;
    int per = (E + nb - 1) / nb;
    int lo = blockIdx.x * per;
    int hi = lo + per; if (hi > E) hi = E;

    for (int t = threadIdx.x; t < ngrp; t += 256) { hcnt[t] = 0; hcur[t] = 0; }
    __syncthreads();

    for (int i = lo + threadIdx.x; i < hi; i += 256)
        atomicAdd(&hcnt[((uint32_t)dst[i]) >> 8], 1u);
    __syncthreads();

    int rot = (blockIdx.x * 37) % (ngrp > 0 ? ngrp : 1);
    for (int k = threadIdx.x; k < ngrp; k += 256) {
        int t = k + rot; if (t >= ngrp) t -= ngrp;
        uint32_t c = hcnt[t];
        hbase[t] = c ? atomicAdd(&gCur[t], c) : 0u;
    }
    __syncthreads();

    for (int i = lo + threadIdx.x; i < hi; i += 256) {
        uint32_t d = (uint32_t)dst[i];
        uint32_t g = d >> 8;
        uint32_t off = hbase[g] + atomicAdd(&hcur[g], 1u);
        if (off < (uint32_t)gcap)
            groupBuf[(size_t)g * gcap + off] = (uint32_t)src[i] | ((d & 255u) << 20);
    }
}

__global__ __launch_bounds__(256) void k_bin2(
    const uint32_t* __restrict__ groupBuf, const uint32_t* __restrict__ gCur,
    uint32_t* __restrict__ bucket, uint32_t* __restrict__ cnt,
    int N, int gcap)
{
    __shared__ uint32_t ncur[256];
    int g = blockIdx.x;
    ncur[threadIdx.x] = 0;
    __syncthreads();
    uint32_t m = gCur[g]; if (m > (uint32_t)gcap) m = gcap;
    int nodebase = g << 8;
    const uint32_t* buf = groupBuf + (size_t)g * gcap;
    for (uint32_t i = threadIdx.x; i < m; i += 256) {
        uint32_t v = buf[i];
        uint32_t nl = v >> 20;
        uint32_t s = v & 0xFFFFFu;
        uint32_t pos = atomicAdd(&ncur[nl], 1u);   // LDS atomic
        if (pos < CAP) bucket[(size_t)(nodebase + (int)nl) * CAP + pos] = s;
    }
    __syncthreads();
    int node = nodebase + threadIdx.x;
    if (node < N) cnt[node] = ncur[threadIdx.x];
}

// ---------------- feature cast f32 -> bf16 (once per call) ----------------

__global__ void k_cast(const float* __restrict__ in, uint32_t* __restrict__ out, int n4) {
    int i = blockIdx.x * blockDim.x + threadIdx.x;
    int stride = gridDim.x * blockDim.x;
    const float4* in4 = (const float4*)in;
    uint2* out2 = (uint2*)out;
    for (; i < n4; i += stride) {
        float4 v = in4[i];
        uint2 r;
        r.x = pack2bf(v.x, v.y);
        r.y = pack2bf(v.z, v.w);
        out2[i] = r;
    }
}

// ---------------- zero row N of X0 and X (invalid-slot target row) ----------------

__global__ void k_zero_row(uint32_t* __restrict__ a, uint32_t* __restrict__ b, int N) {
    int t = threadIdx.x;
    if (t < 64) a[(size_t)N * 64 + t] = 0u;
    else        b[(size_t)N * 64 + (t - 64)] = 0u;
}

// ---------------- weight transpose f32 -> bf16 (once per call) ----------------

__global__ void k_transpose3(const float* __restrict__ w0, const float* __restrict__ w1,
                             const float* __restrict__ w2, u16* __restrict__ t0,
                             u16* __restrict__ t1, u16* __restrict__ t2) {
    const float* w = blockIdx.x == 0 ? w0 : (blockIdx.x == 1 ? w1 : w2);
    u16* o = blockIdx.x == 0 ? t0 : (blockIdx.x == 1 ? t1 : t2);
    for (int idx = threadIdx.x; idx < DIM * DIM; idx += blockDim.x) {
        int r = idx >> 7, c = idx & 127;
        o[c * DIM + r] = f2bf(w[idx]);
    }
}

// ---------------- gather (segment_sum pull) + LayerNorm fused ----------------
// One wave per node; lane handles dims {2l, 2l+1}; f32 accumulation.
// FULLY SCALARIZED addressing: node via readfirstlane -> c is SGPR (s_load),
// slot guard is s_cmp/s_cselect, row base is SALU; inner load is
// global_load_dword v, v_off(l*4), s[base]. ~5 VALU per edge.

__global__ __launch_bounds__(256) void k_gather_ln(
    const uint32_t* __restrict__ xin, const uint32_t* __restrict__ cnt,
    const uint32_t* __restrict__ bucket,
    const int* __restrict__ src, const int* __restrict__ dst,
    const float* __restrict__ gamma, const float* __restrict__ beta,
    uint32_t* __restrict__ h, int N, int E)
{
    int w = threadIdx.x >> 6, l = threadIdx.x & 63;
    // provably wave-uniform node index -> scalar addressing throughout
    int node = __builtin_amdgcn_readfirstlane(blockIdx.x * 4 + w);
    if (node >= N) return;
    uint32_t c = cnt[node];            // uniform -> s_load
    float a0 = 0.f, a1 = 0.f;

    if (__builtin_expect(c > CAP, 0)) {
        // overflow fallback: raw edge scan (never in practice)
        for (int e = 0; e < E; ++e) {
            if (dst[e] == node) {
                uint32_t v = xin[(size_t)src[e] * 64 + l];
                a0 += bflo(v); a1 += bfhi(v);
            }
        }
    } else {
        // lane l holds bucket slot l (slots >= c are garbage, never dereferenced)
        uint32_t bktv = bucket[(size_t)node * CAP + l];
#pragma unroll
        for (int g = 0; g < 4; ++g) {
            if ((uint32_t)(g * 16) < c) {    // uniform branch (s_cmp)
                uint32_t v[16];
#pragma unroll
                for (int i = 0; i < 16; ++i) {
                    const int SLOT = g * 16 + i;
                    // SGPR src index; invalid slots -> zero row N (s_cselect)
                    uint32_t su = (uint32_t)__builtin_amdgcn_readfirstlane(
                        (int)((uint32_t)__builtin_amdgcn_readlane(bktv, SLOT)));
                    su = ((uint32_t)SLOT < c) ? su : (uint32_t)N;
                    const uint32_t* rowp = xin + (size_t)su * 64;  // SALU base
                    v[i] = rowp[l];                                // sbase + l*4
                }
#pragma unroll
                for (int i = 0; i < 16; ++i) { a0 += bflo(v[i]); a1 += bfhi(v[i]); }
            }
        }
    }

    float sum = a0 + a1;
    float sq  = a0 * a0 + a1 * a1;
    for (int off = 32; off; off >>= 1) {
        sum += __shfl_xor(sum, off, 64);
        sq  += __shfl_xor(sq,  off, 64);
    }
    float mean = sum * (1.f / 128.f);
    float var  = sq * (1.f / 128.f) - mean * mean;
    float rs   = rsqrtf(var + 1e-5f);
    float g0 = gamma[2 * l], g1 = gamma[2 * l + 1];
    float b0 = beta[2 * l],  b1 = beta[2 * l + 1];
    float h0 = (a0 - mean) * rs * g0 + b0;
    float h1 = (a1 - mean) * rs * g1 + b1;
    h[(size_t)node * 64 + l] = pack2bf(h0, h1);
}

// ---------------- persistent GEMM: out = relu?(h @ W + b) via MFMA ----------------
// Grid-stride over 32-row tiles; B-fragments + bias hoisted (loaded once per block).

template <int RELU, int OUTF32>
__global__ __launch_bounds__(256) void k_gemm(
    const u16* __restrict__ h, const u16* __restrict__ wt,
    const float* __restrict__ bias, void* __restrict__ outp, int N)
{
    int w = threadIdx.x >> 6, l = threadIdx.x & 63;
    int colbase = (w >> 1) * 64;
    int lr = l & 15, lg = l >> 4;

    short8 bfrag[4][4];
    float bv[4];
#pragma unroll
    for (int ct = 0; ct < 4; ++ct) {
        bv[ct] = bias[colbase + ct * 16 + lr];
#pragma unroll
        for (int kc = 0; kc < 4; ++kc)
            bfrag[ct][kc] = *(const short8*)(wt + (size_t)(colbase + ct * 16 + lr) * DIM + kc * 32 + lg * 8);
    }

    int ntiles = (N + 31) / 32;
    for (int t = blockIdx.x; t < ntiles; t += gridDim.x) {
        int row0 = t * 32 + 16 * (w & 1);
        int ar = row0 + lr;
        if (ar > N - 1) ar = N - 1;

        short8 afrag[4];
#pragma unroll
        for (int kc = 0; kc < 4; ++kc)
            afrag[kc] = *(const short8*)(h + (size_t)ar * DIM + kc * 32 + lg * 8);

#pragma unroll
        for (int ct = 0; ct < 4; ++ct) {
            f32x4 a = {0.f, 0.f, 0.f, 0.f};
#pragma unroll
            for (int kc = 0; kc < 4; ++kc)
                a = __builtin_amdgcn_mfma_f32_16x16x32_bf16(afrag[kc], bfrag[ct][kc], a, 0, 0, 0);
            int col = colbase + ct * 16 + lr;
#pragma unroll
            for (int j = 0; j < 4; ++j) {
                int row = row0 + lg * 4 + j;
                float v = a[j] + bv[ct];
                if (RELU) v = fmaxf(v, 0.f);
                if (row < N) {
                    if (OUTF32) ((float*)outp)[(size_t)row * DIM + col] = v;
                    else        ((u16*)outp)[(size_t)row * DIM + col] = f2bf(v);
                }
            }
        }
    }
}

// ---------------- launch ----------------

extern "C" void kernel_launch(void* const* d_in, const int* in_sizes, int n_in,
                              void* d_out, int out_size, void* d_ws, size_t ws_size,
                              hipStream_t stream) {
    const float* feat = (const float*)d_in[0];
    const int* src  = (const int*)d_in[1];
    const int* dst  = (const int*)d_in[2];
    const float* g1 = (const float*)d_in[3],  *be1 = (const float*)d_in[4];
    const float* W1 = (const float*)d_in[5],  *b1  = (const float*)d_in[6];
    const float* g2 = (const float*)d_in[7],  *be2 = (const float*)d_in[8];
    const float* W2 = (const float*)d_in[9],  *b2  = (const float*)d_in[10];
    const float* g3 = (const float*)d_in[11], *be3 = (const float*)d_in[12];
    const float* W3 = (const float*)d_in[13], *b3  = (const float*)d_in[14];

    int N = in_sizes[0] / DIM;
    int E = in_sizes[1];
    float* out = (float*)d_out;

    int ngrp = (N + 255) >> 8;                 // 391 for N=100000 (max 512)
    int gcap = (E / (ngrp > 0 ? ngrp : 1)) * 3 / 2 + 1024;

    char* ws = (char*)d_ws;
    auto alloc = [&](size_t bytes) {
        char* p = ws;
        ws += (bytes + 255) & ~(size_t)255;
        return p;
    };
    uint32_t* gCur     = (uint32_t*)alloc((size_t)ngrp * 4);
    uint32_t* groupBuf = (uint32_t*)alloc((size_t)ngrp * gcap * 4);
    uint32_t* cnt      = (uint32_t*)alloc((size_t)N * 4);
    uint32_t* bucket   = (uint32_t*)alloc((size_t)N * CAP * 4);
    u16* wt1 = (u16*)alloc(DIM * DIM * 2);
    u16* wt2 = (u16*)alloc(DIM * DIM * 2);
    u16* wt3 = (u16*)alloc(DIM * DIM * 2);
    // N+1 rows: row N is the zero row targeted by invalid slots
    uint32_t* X0 = (uint32_t*)alloc((size_t)(N + 1) * 64 * 4);
    uint32_t* H  = (uint32_t*)alloc((size_t)(N + 1) * 64 * 4);
    uint32_t* X  = (uint32_t*)alloc((size_t)(N + 1) * 64 * 4);

    hipMemsetAsync(gCur, 0, (size_t)ngrp * 4, stream);
    k_bin1<<<256, 256, 0, stream>>>(src, dst, gCur, groupBuf, E, ngrp, gcap);
    k_bin2<<<ngrp, 256, 0, stream>>>(groupBuf, gCur, bucket, cnt, N, gcap);
    k_transpose3<<<3, 256, 0, stream>>>(W1, W2, W3, wt1, wt2, wt3);
    k_cast<<<1024, 256, 0, stream>>>(feat, X0, N * 32);
    k_zero_row<<<1, 128, 0, stream>>>(X0, X, N);

    int gblocks = (N + 3) / 4;

    // gather reads X0/X (+ zero row N), writes H; gemm reads H, writes X — never aliased
    k_gather_ln<<<gblocks, 256, 0, stream>>>(X0, cnt, bucket, src, dst, g1, be1, H, N, E);
    k_gemm<1, 0><<<512, 256, 0, stream>>>((const u16*)H, wt1, b1, X, N);
    k_gather_ln<<<gblocks, 256, 0, stream>>>(X, cnt, bucket, src, dst, g2, be2, H, N, E);
    k_gemm<1, 0><<<512, 256, 0, stream>>>((const u16*)H, wt2, b2, X, N);
    k_gather_ln<<<gblocks, 256, 0, stream>>>(X, cnt, bucket, src, dst, g3, be3, H, N, E);
    k_gemm<0, 1><<<512, 256, 0, stream>>>((const u16*)H, wt3, b3, out, N);
}